// Round 5
// baseline (592.577 us; speedup 1.0000x reference)
//
#include <hip/hip_runtime.h>

#define S_LEN 512
#define BSZ 8
#define NH 8
#define HD 64
#define IN_DIM 512
#define PROJ 2576   // NH*(5*HD+2)
#define SEG 322     // per-head: 5*64+2
#define AST 200     // act row stride in f32: q64,k64,rk64,beta,rbeta
#define SST 208     // scan stage stride: q[0:64) k[64:128) beta[128] rbeta[129] rk[132:196)

typedef __attribute__((ext_vector_type(8))) __bf16 bf16x8;
typedef __attribute__((ext_vector_type(4))) float f32x4;

static __device__ __forceinline__ unsigned short f2bf(float f) {
  unsigned u = __float_as_uint(f);
  unsigned r = (u + 0x7fffu + ((u >> 16) & 1u)) >> 16;
  return (unsigned short)r;
}
static __device__ __forceinline__ float bf2f(unsigned short s) {
  return __uint_as_float(((unsigned)s) << 16);
}
// Orders LDS only; leaves global prefetch loads (vmcnt) in flight.
static __device__ __forceinline__ void barrier_lds_only() {
  asm volatile("s_waitcnt lgkmcnt(0)\n\ts_barrier" ::: "memory");
}

// ---------------- LayerNorm: x (4096x512 f32) -> normed bf16 ----------------
__global__ __launch_bounds__(256) void ln_kernel(const float* __restrict__ x,
                                                 const float* __restrict__ gamma,
                                                 const float* __restrict__ beta,
                                                 unsigned short* __restrict__ out) {
  int wave = threadIdx.x >> 6, lane = threadIdx.x & 63;
  int row = blockIdx.x * 4 + wave;
  const float* xr = x + (size_t)row * IN_DIM + lane * 8;
  float4 a = *(const float4*)xr;
  float4 b = *(const float4*)(xr + 4);
  float vals[8] = {a.x, a.y, a.z, a.w, b.x, b.y, b.z, b.w};
  float s = 0.f, ss = 0.f;
#pragma unroll
  for (int i = 0; i < 8; i++) { s += vals[i]; ss += vals[i] * vals[i]; }
#pragma unroll
  for (int o = 32; o; o >>= 1) { s += __shfl_xor(s, o); ss += __shfl_xor(ss, o); }
  float mu = s * (1.f / 512.f);
  float var = ss * (1.f / 512.f) - mu * mu;
  float rstd = rsqrtf(var + 1e-5f);
  const float* g = gamma + lane * 8;
  const float* be = beta + lane * 8;
  float4 g1 = *(const float4*)g, g2 = *(const float4*)(g + 4);
  float4 b1 = *(const float4*)be, b2 = *(const float4*)(be + 4);
  float gs[8] = {g1.x, g1.y, g1.z, g1.w, g2.x, g2.y, g2.z, g2.w};
  float bs[8] = {b1.x, b1.y, b1.z, b1.w, b2.x, b2.y, b2.z, b2.w};
  union { unsigned short u[8]; uint4 v; } pk;
#pragma unroll
  for (int i = 0; i < 8; i++) pk.u[i] = f2bf((vals[i] - mu) * rstd * gs[i] + bs[i]);
  *(uint4*)(out + (size_t)row * IN_DIM + lane * 8) = pk.v;
}

// ---------------- fused f32 -> bf16 cast of both weight matrices ----------------
__global__ void cast2_kernel(const float* __restrict__ in1, unsigned short* __restrict__ out1, int n1,
                             const float* __restrict__ in2, unsigned short* __restrict__ out2, int n2) {
  int i = blockIdx.x * blockDim.x + threadIdx.x;
  int st = gridDim.x * blockDim.x;
  for (int j = i; j < n1; j += st) out1[j] = f2bf(in1[j]);
  for (int j = i; j < n2; j += st) out2[j] = f2bf(in2[j]);
}

// ---------------- GEMM: C[m][n] = sum_k A[m][k]*B[n][k] (both bf16, K-contig) ----------------
template <int BF16_OUT, int RESID>
__global__ __launch_bounds__(256) void gemm_bt(const unsigned short* __restrict__ A,
                                               const unsigned short* __restrict__ B,
                                               void* __restrict__ Cout,
                                               const float* __restrict__ resid,
                                               int M, int N, int K) {
  __shared__ __align__(16) unsigned short As[64][40];
  __shared__ __align__(16) unsigned short Bs[64][40];
  int tid = threadIdx.x;
  int lane = tid & 63, wave = tid >> 6;
  int m0 = blockIdx.y * 64, n0 = blockIdx.x * 64;
  int srow = tid >> 2, skq = (tid & 3) * 8;
  const unsigned short* Ap = A + (size_t)(m0 + srow) * K + skq;
  const unsigned short* Bp = B + (size_t)(n0 + srow) * K + skq;
  bool bvalid = (n0 + srow) < N;
  f32x4 zero = {0.f, 0.f, 0.f, 0.f};
  f32x4 acc[4];
#pragma unroll
  for (int nt = 0; nt < 4; nt++) acc[nt] = zero;
  int q = lane >> 4, m16 = lane & 15;
  for (int k0 = 0; k0 < K; k0 += 32) {
    uint4 av = *(const uint4*)(Ap + k0);
    uint4 bz = {0u, 0u, 0u, 0u};
    uint4 bv = bvalid ? *(const uint4*)(Bp + k0) : bz;
    *(uint4*)&As[srow][skq] = av;
    *(uint4*)&Bs[srow][skq] = bv;
    __syncthreads();
    bf16x8 af = *(const bf16x8*)&As[wave * 16 + m16][q * 8];
#pragma unroll
    for (int nt = 0; nt < 4; nt++) {
      bf16x8 bfv = *(const bf16x8*)&Bs[nt * 16 + m16][q * 8];
      acc[nt] = __builtin_amdgcn_mfma_f32_16x16x32_bf16(af, bfv, acc[nt], 0, 0, 0);
    }
    __syncthreads();
  }
  int rbase = q * 4;
#pragma unroll
  for (int nt = 0; nt < 4; nt++) {
#pragma unroll
    for (int rr = 0; rr < 4; rr++) {
      int gm = m0 + wave * 16 + rbase + rr;
      int gn = n0 + nt * 16 + m16;
      if (gn < N) {
        float v = acc[nt][rr];
        if (BF16_OUT) {
          ((unsigned short*)Cout)[(size_t)gm * N + gn] = f2bf(v);
        } else {
          float o = v;
          if (RESID) o += resid[(size_t)gm * N + gn];
          ((float*)Cout)[(size_t)gm * N + gn] = o;
        }
      }
    }
  }
}

// ---------------- parallel activations: softmax(q,k,rk), sigmoid(betas) -> f32 ----------------
__global__ __launch_bounds__(256) void act_kernel(const unsigned short* __restrict__ qkvb,
                                                  float* __restrict__ act) {
  int gw = blockIdx.x * 4 + (threadIdx.x >> 6);
  int l = threadIdx.x & 63;
  int m = gw >> 3, hh = gw & 7;
  int t = m >> 3, b = m & 7;
  const unsigned short* src = qkvb + (size_t)m * PROJ + hh * SEG;
  float fq = bf2f(src[l]);
  float fk = bf2f(src[64 + l]);
  float fr = bf2f(src[192 + l]);
  float mq = fq, mk = fk, mr = fr;
#pragma unroll
  for (int o = 32; o; o >>= 1) {
    mq = fmaxf(mq, __shfl_xor(mq, o));
    mk = fmaxf(mk, __shfl_xor(mk, o));
    mr = fmaxf(mr, __shfl_xor(mr, o));
  }
  float eq = __expf(fq - mq), ek = __expf(fk - mk), er = __expf(fr - mr);
  float sq = eq, sk = ek, sr = er;
#pragma unroll
  for (int o = 32; o; o >>= 1) {
    sq += __shfl_xor(sq, o);
    sk += __shfl_xor(sk, o);
    sr += __shfl_xor(sr, o);
  }
  int bh = b * 8 + hh;
  float* dst = act + ((size_t)bh * S_LEN + t) * AST;
  dst[l] = eq * __builtin_amdgcn_rcpf(sq);
  dst[64 + l] = ek * __builtin_amdgcn_rcpf(sk);
  dst[128 + l] = er * __builtin_amdgcn_rcpf(sr);
  if (l < 2) {
    float xv = bf2f(src[320 + l]);
    dst[192 + l] = __builtin_amdgcn_rcpf(1.f + __expf(-xv));
  }
}

// ---------------- scan: wave-private LDS, reg-cached operands, z-only barrier ----------------
// Wave0 (W-scan): owns stage q/k regions; operand vectors k4/q4 cached in VGPRs across uses.
// Wave1 (R-scan): owns rk region + ehb; rk4/e4 cached. Only zbuf (+beta scalars) cross waves.
__global__ __launch_bounds__(128, 1) void scan_kernel(const unsigned short* __restrict__ qkvb,
                                                      const float* __restrict__ act,
                                                      unsigned short* __restrict__ hs) {
  int bh = blockIdx.x;
  int b = bh >> 3, hh = bh & 7;
  int tid = threadIdx.x, l = tid & 63, w = tid >> 6;

  __shared__ __align__(16) float stg[2][SST];
  __shared__ __align__(16) float zbuf[2][64];
  __shared__ __align__(16) float ehb[64];

  const float* arow = act + (size_t)bh * S_LEN * AST;
  const unsigned short* vsrc = qkvb + (size_t)b * PROJ + hh * SEG + (w ? 256 : 128);
  const size_t ts = (size_t)BSZ * PROJ;

  f32x4 M[16];
#pragma unroll
  for (int j = 0; j < 16; j++) M[j] = (f32x4){0.f, 0.f, 0.f, 0.f};

  f32x4 A4[16];  // k (wave0) / rk (wave1) for current step — cached in regs
  f32x4 B4[16];  // q (wave0) / eh (wave1) for current step — cached in regs

  // ---- init: stage t=0, preload operand regs, prefetch t=1 ----
  if (w == 0) {
    stg[0][l] = arow[l];            // q
    stg[0][64 + l] = arow[64 + l];  // k
    if (l < 2) stg[0][128 + l] = arow[192 + l];  // beta, rbeta
  } else {
    stg[0][132 + l] = arow[128 + l];  // rk
    ehb[l] = 1.f;                     // softmax(h0=0): eh=1
  }
  float pA0, pA1, pA2;
  {
    const float* r1 = arow + AST;
    if (w == 0) { pA0 = r1[l]; pA1 = r1[64 + l]; pA2 = r1[192 + (l & 1)]; }
    else        { pA0 = r1[128 + l]; pA1 = 0.f; pA2 = 0.f; }
  }
  unsigned short cvu0 = vsrc[l];
  unsigned short cvu1 = vsrc[ts + l];
  __syncthreads();  // init visibility (incl. rbeta cross-wave), one-time cost

  {
    const f32x4* s40 = (const f32x4*)stg[0];
    if (w == 0) {
#pragma unroll
      for (int j = 0; j < 16; j++) { A4[j] = s40[16 + j]; B4[j] = s40[j]; }
    } else {
#pragma unroll
      for (int j = 0; j < 16; j++) { A4[j] = s40[33 + j]; B4[j] = (f32x4){1.f, 1.f, 1.f, 1.f}; }
    }
  }

  unsigned short* hdst = hs + (size_t)b * 512 + hh * 64 + l;

  for (int t = 0; t < S_LEN; t++) {
    int buf = t & 1, nslot = buf ^ 1;
    // 1. stage writes for t+1 (wave-private regions; beta pair by wave0's lanes 0,1)
    {
      float* st = stg[nslot];
      if (w == 0) {
        st[l] = pA0;
        st[64 + l] = pA1;
        if (l < 2) st[128 + l] = pA2;
      } else {
        st[132 + l] = pA0;
      }
    }
    // 2. global prefetch for t+2 (per-lane addresses -> vector loads, vmcnt only)
    int t2 = (t + 2 < S_LEN) ? (t + 2) : (S_LEN - 1);
    const float* r2 = arow + (size_t)t2 * AST;
    float pB0, pB1, pB2;
    if (w == 0) { pB0 = r2[l]; pB1 = r2[64 + l]; pB2 = r2[192 + (l & 1)]; }
    else        { pB0 = r2[128 + l]; pB1 = 0.f; pB2 = 0.f; }
    unsigned short cvu2 = vsrc[(size_t)t2 * ts + l];

    float cv = bf2f(cvu0);

    if (w == 0) {
      float beta = stg[buf][128];  // uniform-address broadcast read
      // matvec1: vold = M . k
      f32x4 a0 = {0.f, 0.f, 0.f, 0.f}, a1 = a0, a2 = a0, a3 = a0;
#pragma unroll
      for (int j = 0; j < 16; j += 4) {
        a0 += M[j] * A4[j];
        a1 += M[j + 1] * A4[j + 1];
        a2 += M[j + 2] * A4[j + 2];
        a3 += M[j + 3] * A4[j + 3];
      }
      f32x4 vo = (a0 + a1) + (a2 + a3);
      float vold = (vo.x + vo.y) + (vo.z + vo.w);
      float coef = beta * (cv - vold);
      f32x4 c4 = {coef, coef, coef, coef};
      a0 = a1 = a2 = a3 = (f32x4){0.f, 0.f, 0.f, 0.f};
#pragma unroll
      for (int j = 0; j < 16; j += 4) {
        M[j] += c4 * A4[j];          a0 += M[j] * B4[j];
        M[j + 1] += c4 * A4[j + 1];  a1 += M[j + 1] * B4[j + 1];
        M[j + 2] += c4 * A4[j + 2];  a2 += M[j + 2] * B4[j + 2];
        M[j + 3] += c4 * A4[j + 3];  a3 += M[j + 3] * B4[j + 3];
      }
      f32x4 zo = (a0 + a1) + (a2 + a3);
      zbuf[buf][l] = (zo.x + zo.y) + (zo.z + zo.w);
      barrier_lds_only();
      // operand reads for t+1 (slot written at top of THIS body; same-wave in-order)
      const f32x4* sn = (const f32x4*)stg[nslot];
#pragma unroll
      for (int j = 0; j < 16; j++) { A4[j] = sn[16 + j]; B4[j] = sn[j]; }
    } else {
      float rbeta = stg[buf][129];
      // matvec1: rvold = M . rk
      f32x4 a0 = {0.f, 0.f, 0.f, 0.f}, a1 = a0, a2 = a0, a3 = a0;
#pragma unroll
      for (int j = 0; j < 16; j += 4) {
        a0 += M[j] * A4[j];
        a1 += M[j + 1] * A4[j + 1];
        a2 += M[j + 2] * A4[j + 2];
        a3 += M[j + 3] * A4[j + 3];
      }
      f32x4 vo = (a0 + a1) + (a2 + a3);
      float rvold = (vo.x + vo.y) + (vo.z + vo.w);
      float rcoef = rbeta * (cv - rvold);
      f32x4 c4 = {rcoef, rcoef, rcoef, rcoef};
      f32x4 s0 = {0.f, 0.f, 0.f, 0.f}, s1 = s0, s2v = s0, s3 = s0;
      a0 = a1 = a2 = a3 = (f32x4){0.f, 0.f, 0.f, 0.f};
#pragma unroll
      for (int j = 0; j < 16; j += 4) {
        M[j] += c4 * A4[j];          a0 += M[j] * B4[j];      s0 += B4[j];
        M[j + 1] += c4 * A4[j + 1];  a1 += M[j + 1] * B4[j + 1]; s1 += B4[j + 1];
        M[j + 2] += c4 * A4[j + 2];  a2 += M[j + 2] * B4[j + 2]; s2v += B4[j + 2];
        M[j + 3] += c4 * A4[j + 3];  a3 += M[j + 3] * B4[j + 3]; s3 += B4[j + 3];
      }
      f32x4 ho = (a0 + a1) + (a2 + a3);
      f32x4 so = (s0 + s1) + (s2v + s3);
      float hp = (ho.x + ho.y) + (ho.z + ho.w);
      float sm = (so.x + so.y) + (so.z + so.w);
      barrier_lds_only();
      float z = zbuf[buf][l];
      float h = z + hp * __builtin_amdgcn_rcpf(sm);
      hdst[(size_t)t * BSZ * 512] = f2bf(h);
      ehb[l] = __expf(h - 20.f);  // shift-invariant (eh/sum exact)
      // operand reads for t+1: rk from slot written this body; eh just written (same wave)
      const f32x4* sn = (const f32x4*)stg[nslot];
      const f32x4* e4 = (const f32x4*)ehb;
#pragma unroll
      for (int j = 0; j < 16; j++) { A4[j] = sn[33 + j]; B4[j] = e4[j]; }
    }

    pA0 = pB0; pA1 = pB1; pA2 = pB2;
    cvu0 = cvu1; cvu1 = cvu2;
  }
}

extern "C" void kernel_launch(void* const* d_in, const int* in_sizes, int n_in,
                              void* d_out, int out_size, void* d_ws, size_t ws_size,
                              hipStream_t stream) {
  const float* x = (const float*)d_in[0];
  const float* W_slow = (const float*)d_in[1];
  const float* W_out = (const float*)d_in[2];
  const float* gamma = (const float*)d_in[3];
  const float* beta = (const float*)d_in[4];

  char* ws = (char*)d_ws;
  size_t off = 0;
  unsigned short* normed = (unsigned short*)(ws + off); off += (size_t)4096 * 512 * 2;
  unsigned short* Wslow_b = (unsigned short*)(ws + off); off += (size_t)PROJ * 512 * 2;
  unsigned short* Wout_b = (unsigned short*)(ws + off); off += (size_t)512 * 512 * 2;
  unsigned short* qkvb = (unsigned short*)(ws + off); off += (size_t)4096 * PROJ * 2;
  float* act = (float*)(ws + off); off += (size_t)64 * S_LEN * AST * 4;
  unsigned short* hsb = normed;  // normed is dead after gemm1; reuse for hs

  hipLaunchKernelGGL(ln_kernel, dim3(1024), dim3(256), 0, stream, x, gamma, beta, normed);
  hipLaunchKernelGGL(cast2_kernel, dim3(512), dim3(256), 0, stream,
                     W_slow, Wslow_b, PROJ * 512, W_out, Wout_b, 512 * 512);
  hipLaunchKernelGGL((gemm_bt<1, 0>), dim3((PROJ + 63) / 64, 4096 / 64), dim3(256), 0, stream,
                     normed, Wslow_b, (void*)qkvb, (const float*)nullptr, 4096, PROJ, 512);
  hipLaunchKernelGGL(act_kernel, dim3(8192), dim3(256), 0, stream, qkvb, act);
  hipLaunchKernelGGL(scan_kernel, dim3(64), dim3(128), 0, stream, qkvb, act, hsb);
  hipLaunchKernelGGL((gemm_bt<0, 1>), dim3(512 / 64, 4096 / 64), dim3(256), 0, stream,
                     hsb, Wout_b, d_out, x, 4096, 512, 512);
}

// Round 6
// 521.902 us; speedup vs baseline: 1.1354x; 1.1354x over previous
//
#include <hip/hip_runtime.h>

#define S_LEN 512
#define BSZ 8
#define NH 8
#define HD 64
#define IN_DIM 512
#define PROJ 2576   // NH*(5*HD+2)
#define SEG 322     // per-head: 5*64+2
#define AST 200     // act row stride in f32: q64,k64,rk64,beta,rbeta
#define SST 208     // scan stage: q[0:64) k[64:128) beta@128 rbeta@129 pad rk[132:196)

typedef __attribute__((ext_vector_type(8))) __bf16 bf16x8;
typedef __attribute__((ext_vector_type(4))) float f32x4;

static __device__ __forceinline__ unsigned short f2bf(float f) {
  unsigned u = __float_as_uint(f);
  unsigned r = (u + 0x7fffu + ((u >> 16) & 1u)) >> 16;
  return (unsigned short)r;
}
static __device__ __forceinline__ float bf2f(unsigned short s) {
  return __uint_as_float(((unsigned)s) << 16);
}
// Orders LDS only; leaves global prefetch loads (vmcnt) in flight.
static __device__ __forceinline__ void barrier_lds_only() {
  asm volatile("s_waitcnt lgkmcnt(0)\n\ts_barrier" ::: "memory");
}

// ---------------- LayerNorm: x (4096x512 f32) -> normed bf16 ----------------
__global__ __launch_bounds__(256) void ln_kernel(const float* __restrict__ x,
                                                 const float* __restrict__ gamma,
                                                 const float* __restrict__ beta,
                                                 unsigned short* __restrict__ out) {
  int wave = threadIdx.x >> 6, lane = threadIdx.x & 63;
  int row = blockIdx.x * 4 + wave;
  const float* xr = x + (size_t)row * IN_DIM + lane * 8;
  float4 a = *(const float4*)xr;
  float4 b = *(const float4*)(xr + 4);
  float vals[8] = {a.x, a.y, a.z, a.w, b.x, b.y, b.z, b.w};
  float s = 0.f, ss = 0.f;
#pragma unroll
  for (int i = 0; i < 8; i++) { s += vals[i]; ss += vals[i] * vals[i]; }
#pragma unroll
  for (int o = 32; o; o >>= 1) { s += __shfl_xor(s, o); ss += __shfl_xor(ss, o); }
  float mu = s * (1.f / 512.f);
  float var = ss * (1.f / 512.f) - mu * mu;
  float rstd = rsqrtf(var + 1e-5f);
  const float* g = gamma + lane * 8;
  const float* be = beta + lane * 8;
  float4 g1 = *(const float4*)g, g2 = *(const float4*)(g + 4);
  float4 b1 = *(const float4*)be, b2 = *(const float4*)(be + 4);
  float gs[8] = {g1.x, g1.y, g1.z, g1.w, g2.x, g2.y, g2.z, g2.w};
  float bs[8] = {b1.x, b1.y, b1.z, b1.w, b2.x, b2.y, b2.z, b2.w};
  union { unsigned short u[8]; uint4 v; } pk;
#pragma unroll
  for (int i = 0; i < 8; i++) pk.u[i] = f2bf((vals[i] - mu) * rstd * gs[i] + bs[i]);
  *(uint4*)(out + (size_t)row * IN_DIM + lane * 8) = pk.v;
}

// ---------------- fused f32 -> bf16 cast of both weight matrices ----------------
__global__ void cast2_kernel(const float* __restrict__ in1, unsigned short* __restrict__ out1, int n1,
                             const float* __restrict__ in2, unsigned short* __restrict__ out2, int n2) {
  int i = blockIdx.x * blockDim.x + threadIdx.x;
  int st = gridDim.x * blockDim.x;
  for (int j = i; j < n1; j += st) out1[j] = f2bf(in1[j]);
  for (int j = i; j < n2; j += st) out2[j] = f2bf(in2[j]);
}

// ---------------- GEMM: C[m][n] = sum_k A[m][k]*B[n][k] (both bf16, K-contig) ----------------
template <int BF16_OUT, int RESID>
__global__ __launch_bounds__(256) void gemm_bt(const unsigned short* __restrict__ A,
                                               const unsigned short* __restrict__ B,
                                               void* __restrict__ Cout,
                                               const float* __restrict__ resid,
                                               int M, int N, int K) {
  __shared__ __align__(16) unsigned short As[64][40];
  __shared__ __align__(16) unsigned short Bs[64][40];
  int tid = threadIdx.x;
  int lane = tid & 63, wave = tid >> 6;
  int m0 = blockIdx.y * 64, n0 = blockIdx.x * 64;
  int srow = tid >> 2, skq = (tid & 3) * 8;
  const unsigned short* Ap = A + (size_t)(m0 + srow) * K + skq;
  const unsigned short* Bp = B + (size_t)(n0 + srow) * K + skq;
  bool bvalid = (n0 + srow) < N;
  f32x4 zero = {0.f, 0.f, 0.f, 0.f};
  f32x4 acc[4];
#pragma unroll
  for (int nt = 0; nt < 4; nt++) acc[nt] = zero;
  int q = lane >> 4, m16 = lane & 15;
  for (int k0 = 0; k0 < K; k0 += 32) {
    uint4 av = *(const uint4*)(Ap + k0);
    uint4 bz = {0u, 0u, 0u, 0u};
    uint4 bv = bvalid ? *(const uint4*)(Bp + k0) : bz;
    *(uint4*)&As[srow][skq] = av;
    *(uint4*)&Bs[srow][skq] = bv;
    __syncthreads();
    bf16x8 af = *(const bf16x8*)&As[wave * 16 + m16][q * 8];
#pragma unroll
    for (int nt = 0; nt < 4; nt++) {
      bf16x8 bfv = *(const bf16x8*)&Bs[nt * 16 + m16][q * 8];
      acc[nt] = __builtin_amdgcn_mfma_f32_16x16x32_bf16(af, bfv, acc[nt], 0, 0, 0);
    }
    __syncthreads();
  }
  int rbase = q * 4;
#pragma unroll
  for (int nt = 0; nt < 4; nt++) {
#pragma unroll
    for (int rr = 0; rr < 4; rr++) {
      int gm = m0 + wave * 16 + rbase + rr;
      int gn = n0 + nt * 16 + m16;
      if (gn < N) {
        float v = acc[nt][rr];
        if (BF16_OUT) {
          ((unsigned short*)Cout)[(size_t)gm * N + gn] = f2bf(v);
        } else {
          float o = v;
          if (RESID) o += resid[(size_t)gm * N + gn];
          ((float*)Cout)[(size_t)gm * N + gn] = o;
        }
      }
    }
  }
}

// ---------------- parallel activations: softmax(q,k,rk), sigmoid(betas) -> f32 ----------------
__global__ __launch_bounds__(256) void act_kernel(const unsigned short* __restrict__ qkvb,
                                                  float* __restrict__ act) {
  int gw = blockIdx.x * 4 + (threadIdx.x >> 6);
  int l = threadIdx.x & 63;
  int m = gw >> 3, hh = gw & 7;
  int t = m >> 3, b = m & 7;
  const unsigned short* src = qkvb + (size_t)m * PROJ + hh * SEG;
  float fq = bf2f(src[l]);
  float fk = bf2f(src[64 + l]);
  float fr = bf2f(src[192 + l]);
  float mq = fq, mk = fk, mr = fr;
#pragma unroll
  for (int o = 32; o; o >>= 1) {
    mq = fmaxf(mq, __shfl_xor(mq, o));
    mk = fmaxf(mk, __shfl_xor(mk, o));
    mr = fmaxf(mr, __shfl_xor(mr, o));
  }
  float eq = __expf(fq - mq), ek = __expf(fk - mk), er = __expf(fr - mr);
  float sq = eq, sk = ek, sr = er;
#pragma unroll
  for (int o = 32; o; o >>= 1) {
    sq += __shfl_xor(sq, o);
    sk += __shfl_xor(sk, o);
    sr += __shfl_xor(sr, o);
  }
  int bh = b * 8 + hh;
  float* dst = act + ((size_t)bh * S_LEN + t) * AST;
  dst[l] = eq * __builtin_amdgcn_rcpf(sq);
  dst[64 + l] = ek * __builtin_amdgcn_rcpf(sk);
  dst[128 + l] = er * __builtin_amdgcn_rcpf(sr);
  if (l < 2) {
    float xv = bf2f(src[320 + l]);
    dst[192 + l] = __builtin_amdgcn_rcpf(1.f + __expf(-xv));
  }
}

// ---------------- scan: wave-private LDS, depth-4 prefetch rotation, z-only barrier ----------------
// Wave0 (W-scan): stages q/k/betas; wave1 (R-scan): stages rk, owns ehb. Operands read
// inline from LDS in the fma loops (compiler interleaves lgkmcnt). Global loads are
// rotated pA<-pB<-pC<-new so the load->ds_write gap is 3 bodies (> HBM latency).
__global__ __launch_bounds__(128, 1) void scan_kernel(const unsigned short* __restrict__ qkvb,
                                                      const float* __restrict__ act,
                                                      unsigned short* __restrict__ hs) {
  int bh = blockIdx.x;
  int b = bh >> 3, hh = bh & 7;
  int tid = threadIdx.x, l = tid & 63, w = tid >> 6;

  __shared__ __align__(16) float stg[2][SST];
  __shared__ __align__(16) float zbuf[2][64];
  __shared__ __align__(16) float ehb[64];

  const float* arow = act + (size_t)bh * S_LEN * AST;
  const unsigned short* vsrc = qkvb + (size_t)b * PROJ + hh * SEG + (w ? 256 : 128);
  const size_t ts = (size_t)BSZ * PROJ;

  f32x4 M[16];
#pragma unroll
  for (int j = 0; j < 16; j++) M[j] = (f32x4){0.f, 0.f, 0.f, 0.f};

  // ---- init: stage t=0; rotation regs hold rows t+1..t+3; cv regs rows t..t+2 ----
  if (w == 0) {
    stg[0][l] = arow[l];
    stg[0][64 + l] = arow[64 + l];
    if (l < 2) stg[0][128 + l] = arow[192 + l];
  } else {
    stg[0][132 + l] = arow[128 + l];
    ehb[l] = 1.f;  // softmax(h0=0): eh=1; sum folds naturally
  }
  float pA0, pA1, pA2, pB0, pB1, pB2, pC0, pC1, pC2;
  {
    const float* r1 = arow + AST;
    const float* r2 = arow + 2 * AST;
    const float* r3 = arow + 3 * AST;
    if (w == 0) {
      pA0 = r1[l]; pA1 = r1[64 + l]; pA2 = r1[192 + (l & 1)];
      pB0 = r2[l]; pB1 = r2[64 + l]; pB2 = r2[192 + (l & 1)];
      pC0 = r3[l]; pC1 = r3[64 + l]; pC2 = r3[192 + (l & 1)];
    } else {
      pA0 = r1[128 + l]; pB0 = r2[128 + l]; pC0 = r3[128 + l];
      pA1 = pA2 = pB1 = pB2 = pC1 = pC2 = 0.f;
    }
  }
  unsigned short cvu0 = vsrc[l];
  unsigned short cvu1 = vsrc[ts + l];
  unsigned short cvu2 = vsrc[2 * ts + l];
  __syncthreads();  // one-time init visibility

  unsigned short* hdst = hs + (size_t)b * 512 + hh * 64 + l;

  for (int t = 0; t < S_LEN; t++) {
    int buf = t & 1, nslot = buf ^ 1;
    // 1. stage writes for t+1 (pA loaded 3 bodies ago -> vmcnt satisfied)
    {
      float* st = stg[nslot];
      if (w == 0) {
        st[l] = pA0;
        st[64 + l] = pA1;
        if (l < 2) st[128 + l] = pA2;
      } else {
        st[132 + l] = pA0;
      }
    }
    // 2. global prefetch: act row t+4, v row t+3 (pure reg destinations, vmcnt only)
    int t4 = (t + 4 < S_LEN) ? (t + 4) : (S_LEN - 1);
    int t3 = (t + 3 < S_LEN) ? (t + 3) : (S_LEN - 1);
    const float* r4 = arow + (size_t)t4 * AST;
    float pN0, pN1, pN2;
    if (w == 0) { pN0 = r4[l]; pN1 = r4[64 + l]; pN2 = r4[192 + (l & 1)]; }
    else        { pN0 = r4[128 + l]; pN1 = 0.f; pN2 = 0.f; }
    unsigned short cvuN = vsrc[(size_t)t3 * ts + l];

    float cv = bf2f(cvu0);
    const f32x4* s4 = (const f32x4*)stg[buf];

    if (w == 0) {
      float beta = stg[buf][128];
      f32x4 kk[16];
      f32x4 a0 = {0.f, 0.f, 0.f, 0.f}, a1 = a0, a2 = a0, a3 = a0;
#pragma unroll
      for (int j = 0; j < 16; j += 4) {
        kk[j] = s4[16 + j];         a0 += M[j] * kk[j];
        kk[j + 1] = s4[17 + j];     a1 += M[j + 1] * kk[j + 1];
        kk[j + 2] = s4[18 + j];     a2 += M[j + 2] * kk[j + 2];
        kk[j + 3] = s4[19 + j];     a3 += M[j + 3] * kk[j + 3];
      }
      f32x4 vo = (a0 + a1) + (a2 + a3);
      float vold = (vo.x + vo.y) + (vo.z + vo.w);
      float coef = beta * (cv - vold);
      f32x4 c4 = {coef, coef, coef, coef};
      a0 = a1 = a2 = a3 = (f32x4){0.f, 0.f, 0.f, 0.f};
#pragma unroll
      for (int j = 0; j < 16; j += 4) {
        M[j] += c4 * kk[j];          a0 += M[j] * s4[j];
        M[j + 1] += c4 * kk[j + 1];  a1 += M[j + 1] * s4[j + 1];
        M[j + 2] += c4 * kk[j + 2];  a2 += M[j + 2] * s4[j + 2];
        M[j + 3] += c4 * kk[j + 3];  a3 += M[j + 3] * s4[j + 3];
      }
      f32x4 zo = (a0 + a1) + (a2 + a3);
      zbuf[buf][l] = (zo.x + zo.y) + (zo.z + zo.w);
      barrier_lds_only();
    } else {
      float rbeta = stg[buf][129];
      f32x4 kk[16];
      f32x4 a0 = {0.f, 0.f, 0.f, 0.f}, a1 = a0, a2 = a0, a3 = a0;
#pragma unroll
      for (int j = 0; j < 16; j += 4) {
        kk[j] = s4[33 + j];         a0 += M[j] * kk[j];
        kk[j + 1] = s4[34 + j];     a1 += M[j + 1] * kk[j + 1];
        kk[j + 2] = s4[35 + j];     a2 += M[j + 2] * kk[j + 2];
        kk[j + 3] = s4[36 + j];     a3 += M[j + 3] * kk[j + 3];
      }
      f32x4 vo = (a0 + a1) + (a2 + a3);
      float rvold = (vo.x + vo.y) + (vo.z + vo.w);
      float rcoef = rbeta * (cv - rvold);
      f32x4 c4 = {rcoef, rcoef, rcoef, rcoef};
      const f32x4* e4 = (const f32x4*)ehb;
      f32x4 s0 = {0.f, 0.f, 0.f, 0.f}, s1 = s0, s2v = s0, s3 = s0;
      a0 = a1 = a2 = a3 = (f32x4){0.f, 0.f, 0.f, 0.f};
#pragma unroll
      for (int j = 0; j < 16; j += 4) {
        f32x4 e0 = e4[j], e1 = e4[j + 1], e2 = e4[j + 2], e3 = e4[j + 3];
        M[j] += c4 * kk[j];          a0 += M[j] * e0;          s0 += e0;
        M[j + 1] += c4 * kk[j + 1];  a1 += M[j + 1] * e1;      s1 += e1;
        M[j + 2] += c4 * kk[j + 2];  a2 += M[j + 2] * e2;      s2v += e2;
        M[j + 3] += c4 * kk[j + 3];  a3 += M[j + 3] * e3;      s3 += e3;
      }
      f32x4 ho = (a0 + a1) + (a2 + a3);
      f32x4 so = (s0 + s1) + (s2v + s3);
      float hp = (ho.x + ho.y) + (ho.z + ho.w);
      float sm = (so.x + so.y) + (so.z + so.w);
      barrier_lds_only();
      float z = zbuf[buf][l];
      float h = z + hp * __builtin_amdgcn_rcpf(sm);
      hdst[(size_t)t * BSZ * 512] = f2bf(h);
      ehb[l] = __expf(h - 20.f);  // shift-invariant; same-wave read next body
    }

    pA0 = pB0; pA1 = pB1; pA2 = pB2;
    pB0 = pC0; pB1 = pC1; pB2 = pC2;
    pC0 = pN0; pC1 = pN1; pC2 = pN2;
    cvu0 = cvu1; cvu1 = cvu2; cvu2 = cvuN;
  }
}

extern "C" void kernel_launch(void* const* d_in, const int* in_sizes, int n_in,
                              void* d_out, int out_size, void* d_ws, size_t ws_size,
                              hipStream_t stream) {
  const float* x = (const float*)d_in[0];
  const float* W_slow = (const float*)d_in[1];
  const float* W_out = (const float*)d_in[2];
  const float* gamma = (const float*)d_in[3];
  const float* beta = (const float*)d_in[4];

  char* ws = (char*)d_ws;
  size_t off = 0;
  unsigned short* normed = (unsigned short*)(ws + off); off += (size_t)4096 * 512 * 2;
  unsigned short* Wslow_b = (unsigned short*)(ws + off); off += (size_t)PROJ * 512 * 2;
  unsigned short* Wout_b = (unsigned short*)(ws + off); off += (size_t)512 * 512 * 2;
  unsigned short* qkvb = (unsigned short*)(ws + off); off += (size_t)4096 * PROJ * 2;
  float* act = (float*)(ws + off); off += (size_t)64 * S_LEN * AST * 4;
  unsigned short* hsb = normed;  // normed is dead after gemm1; reuse for hs

  hipLaunchKernelGGL(ln_kernel, dim3(1024), dim3(256), 0, stream, x, gamma, beta, normed);
  hipLaunchKernelGGL(cast2_kernel, dim3(512), dim3(256), 0, stream,
                     W_slow, Wslow_b, PROJ * 512, W_out, Wout_b, 512 * 512);
  hipLaunchKernelGGL((gemm_bt<1, 0>), dim3((PROJ + 63) / 64, 4096 / 64), dim3(256), 0, stream,
                     normed, Wslow_b, (void*)qkvb, (const float*)nullptr, 4096, PROJ, 512);
  hipLaunchKernelGGL(act_kernel, dim3(8192), dim3(256), 0, stream, qkvb, act);
  hipLaunchKernelGGL(scan_kernel, dim3(64), dim3(128), 0, stream, qkvb, act, hsb);
  hipLaunchKernelGGL((gemm_bt<0, 1>), dim3(512 / 64, 4096 / 64), dim3(256), 0, stream,
                     hsb, Wout_b, d_out, x, 4096, 512, 512);
}